// Round 4
// baseline (486.491 us; speedup 1.0000x reference)
//
#include <hip/hip_runtime.h>

// ---------------- problem constants ----------------
#define T_STEPS 16
#define BATCH   64
#define M_ROWS  1024          // T*B
#define K_DIM   60000
#define N1      200
#define N2      50
#define N3      2
#define NPAD    256           // W1 rows padded (rows 200..255 zero)
#define HN      (M_ROWS * N1) // 204800 elems per [m][n] slab

typedef __attribute__((ext_vector_type(8))) short    bf16x8;
typedef __attribute__((ext_vector_type(4))) float    f32x4;
typedef __attribute__((ext_vector_type(8))) unsigned short u16x8;

static __device__ __forceinline__ unsigned short f2bf(float f) {
    unsigned int u = __float_as_uint(f);
    u += 0x7FFFu + ((u >> 16) & 1u);      // RNE f32 -> bf16
    return (unsigned short)(u >> 16);
}

// Kernel 0: W1 f32 -> bf16, padded to 256 rows (rows >=200 zero).
// 15.36M elems, 8 per thread, grid 7500 x 256 exact.
__global__ __launch_bounds__(256)
void cvt_w1(const float* __restrict__ w1, unsigned short* __restrict__ w1b) {
    const size_t e = ((size_t)blockIdx.x * 256 + threadIdx.x) * 8;
    if (e >= (size_t)NPAD * K_DIM) return;
    const int row = (int)(e / K_DIM);
    u16x8 v = (u16x8){0, 0, 0, 0, 0, 0, 0, 0};
    if (row < N1) {
        float4 f0 = *(const float4*)(w1 + e);
        float4 f1 = *(const float4*)(w1 + e + 4);
        #pragma unroll
        for (int q = 0; q < 4; ++q) { v[q] = f2bf(f0[q]); v[q + 4] = f2bf(f1[q]); }
    }
    *(u16x8*)(w1b + e) = v;
}

// Kernel 1: part[s] = X[:, seg_s] @ W1b[:, seg_s].T  -- no LDS, no barriers.
// Block 256 = 4 waves. Block tile: 256 m x 64 n; each wave owns 64 m x 64 n.
// X (f32) loaded straight into A-fragments (16 rows x 128B contiguous,
// coalesced), converted in-register; W1b (bf16) loaded straight into
// B-fragments (L2/L3 resident). 1-deep register prefetch hides HBM latency
// across 12 independent waves/CU.
template <int KSEG, int KSTEPS, int KSPLIT>
__global__ __launch_bounds__(256, 3)
void gemm_direct(const float* __restrict__ x,
                 const unsigned short* __restrict__ w1b,
                 float* __restrict__ part) {
    const int tid = threadIdx.x;
    const int l   = tid & 63;
    const int wv  = tid >> 6;

    // XCD-chunked swizzle (bijective: 16*KSPLIT % 8 == 0): consecutive logical
    // ids (same s, same nt) land on one XCD -> W1 k-seg stays in that L2.
    const int hw      = blockIdx.y * 16 + blockIdx.x;
    const int chunk   = (16 * KSPLIT) / 8;
    const int logical = (hw & 7) * chunk + (hw >> 3);
    const int s  = logical >> 4;
    const int nt = (logical >> 2) & 3;
    const int mt = logical & 3;

    const int m0 = mt * 256 + wv * 64;     // wave's 64 m-rows
    const int n0 = nt * 64;
    const int k0 = s * KSEG;

    const int ra   = l & 15;               // fragment row
    const int koff = (l >> 4) * 8;         // fragment k-offset (elements)

    f32x4 acc[4][4];
    #pragma unroll
    for (int i = 0; i < 4; ++i)
        #pragma unroll
        for (int j = 0; j < 4; ++j) acc[i][j] = (f32x4){0.f, 0.f, 0.f, 0.f};

    const float* ax[4];
    const unsigned short* bx[4];
    #pragma unroll
    for (int fm = 0; fm < 4; ++fm)
        ax[fm] = x + (size_t)(m0 + fm * 16 + ra) * K_DIM + k0 + koff;
    #pragma unroll
    for (int fn = 0; fn < 4; ++fn)
        bx[fn] = w1b + (size_t)(n0 + fn * 16 + ra) * K_DIM + k0 + koff;

    // prefetch step 0
    float4 a0[4], a1[4];
    bf16x8 bb[4];
    #pragma unroll
    for (int fm = 0; fm < 4; ++fm) {
        a0[fm] = *(const float4*)ax[fm];
        a1[fm] = *(const float4*)(ax[fm] + 4);
    }
    #pragma unroll
    for (int fn = 0; fn < 4; ++fn) bb[fn] = *(const bf16x8*)bx[fn];

    for (int it = 0; it < KSTEPS; ++it) {
        const bool more = (it + 1) < KSTEPS;
        const int  noff = (it + 1) * 32;

        // convert current A (frees a0/a1 for the next prefetch)
        bf16x8 af[4];
        #pragma unroll
        for (int fm = 0; fm < 4; ++fm) {
            u16x8 v;
            #pragma unroll
            for (int q = 0; q < 4; ++q) { v[q] = f2bf(a0[fm][q]); v[q + 4] = f2bf(a1[fm][q]); }
            af[fm] = (bf16x8)v;
        }
        // issue next A loads (in flight during MFMA)
        if (more) {
            #pragma unroll
            for (int fm = 0; fm < 4; ++fm) {
                a0[fm] = *(const float4*)(ax[fm] + noff);
                a1[fm] = *(const float4*)(ax[fm] + noff + 4);
            }
        }
        // MFMA on current fragments
        #pragma unroll
        for (int fn = 0; fn < 4; ++fn) {
            bf16x8 bf = bb[fn];
            #pragma unroll
            for (int fm = 0; fm < 4; ++fm)
                acc[fm][fn] = __builtin_amdgcn_mfma_f32_16x16x32_bf16(af[fm], bf, acc[fm][fn], 0, 0, 0);
        }
        // issue next B loads (consumed after next iter's cvt+A-issue)
        if (more) {
            #pragma unroll
            for (int fn = 0; fn < 4; ++fn)
                bb[fn] = *(const bf16x8*)(bx[fn] + noff);
        }
    }

    // epilogue: store cols < 200, part layout [s][m][n], ld = 200
    const int crow = (l >> 4) * 4;
    const int ccol = l & 15;
    #pragma unroll
    for (int fm = 0; fm < 4; ++fm)
        #pragma unroll
        for (int fn = 0; fn < 4; ++fn) {
            const int gn = n0 + fn * 16 + ccol;
            if (gn < N1) {
                const int gm = m0 + fm * 16 + crow;
                float* p = part + (size_t)s * HN + (size_t)gm * N1 + gn;
                #pragma unroll
                for (int r = 0; r < 4; ++r) p[(size_t)r * N1] = acc[fm][fn][r];
            }
        }
}

// Kernel 2: fused tail. One block per batch b: deterministic s-ascending
// reduction of partials, LIF-1 recurrence (thread = neuron i), spike masks
// via ballot -> LDS, then wave 0 runs tiny layers 2-3 sequentially.
template <int KSPLIT>
__global__ __launch_bounds__(256)
void tail_fused(const float* __restrict__ part,
                const float* __restrict__ w2, const float* __restrict__ w3,
                float* __restrict__ out) {
    __shared__ unsigned long long msk[4];

    const int b    = blockIdx.x;
    const int i    = threadIdx.x;
    const int wv   = i >> 6;
    const int lane = i & 63;

    float v1 = 0.f;
    float v2 = 0.f;              // meaningful on wave 0, lanes < 50
    float v3 = 0.f;              // meaningful on wave 0, lanes < 2

    for (int t = 0; t < T_STEPS; ++t) {
        // ---- layer 1: reduce partials (fixed s order), LIF update ----
        float h = 0.f;
        if (i < N1) {
            const size_t base = (size_t)(t * BATCH + b) * N1 + i;
            #pragma unroll
            for (int s = 0; s < KSPLIT; ++s)
                h += part[(size_t)s * HN + base];
        }
        v1 += (h - v1) * 0.5f;
        bool sp1 = (v1 - 1.0f) >= 0.f;
        unsigned long long m1 = __ballot(sp1);
        if (sp1) v1 = 0.f;
        if (lane == 0) msk[wv] = m1;
        __syncthreads();

        // ---- layers 2+3 on wave 0 only ----
        if (wv == 0) {
            float h2 = 0.f;
            if (lane < N2) {
                #pragma unroll
                for (int w = 0; w < 4; ++w) {
                    unsigned long long m = msk[w];
                    while (m) {
                        int lz = __builtin_ctzll(m);
                        m &= m - 1;
                        h2 += w2[lane * N1 + (w * 64 + lz)];
                    }
                }
            }
            v2 += (h2 - v2) * 0.5f;
            bool sp2 = (v2 - 1.0f) >= 0.f;          // lanes >= 50: v2 == 0, false
            unsigned long long bal2 = __ballot(sp2);
            if (sp2) v2 = 0.f;

            float h3 = 0.f;
            if (lane < N3) {
                unsigned long long m = bal2;
                while (m) {
                    int j = __builtin_ctzll(m);
                    m &= m - 1;
                    h3 += w3[lane * N2 + j];
                }
            }
            v3 += (h3 - v3) * 0.5f;
            bool sp3 = (v3 - 1.0f) >= 0.f;
            if (lane < N3)
                out[(size_t)(t * BATCH + b) * N3 + lane] = sp3 ? 1.f : 0.f;
            if (sp3) v3 = 0.f;
        }
        __syncthreads();   // msk reused next t
    }
}

extern "C" void kernel_launch(void* const* d_in, const int* in_sizes, int n_in,
                              void* d_out, int out_size, void* d_ws, size_t ws_size,
                              hipStream_t stream) {
    const float* x  = (const float*)d_in[0];   // [16,64,150,400] -> [1024][60000]
    const float* w1 = (const float*)d_in[1];   // [200][60000]
    const float* w2 = (const float*)d_in[2];   // [50][200]
    const float* w3 = (const float*)d_in[3];   // [2][50]
    float* out = (float*)d_out;                // [16][64][2]

    // ws: part [KSPLIT][1024][200] f32, then W1b [256][60000] bf16
    const size_t w1b_bytes = (size_t)NPAD * K_DIM * 2;           // 30.72 MB
    const size_t need75 = (size_t)75 * HN * 4 + w1b_bytes;       // 92.2 MB
    const bool big = ws_size >= need75;                          // fallback: 51.2 MB

    if (big) {
        float* part = (float*)d_ws;
        unsigned short* w1b = (unsigned short*)((char*)d_ws + (size_t)75 * HN * 4);
        cvt_w1<<<7500, 256, 0, stream>>>(w1, w1b);
        dim3 g(16, 75);
        gemm_direct<800, 25, 75><<<g, 256, 0, stream>>>(x, w1b, part);
        tail_fused<75><<<BATCH, 256, 0, stream>>>(part, w2, w3, out);
    } else {
        float* part = (float*)d_ws;
        unsigned short* w1b = (unsigned short*)((char*)d_ws + (size_t)25 * HN * 4);
        cvt_w1<<<7500, 256, 0, stream>>>(w1, w1b);
        dim3 g(16, 25);
        gemm_direct<2400, 75, 25><<<g, 256, 0, stream>>>(x, w1b, part);
        tail_fused<25><<<BATCH, 256, 0, stream>>>(part, w2, w3, out);
    }
}

// Round 5
// 248.826 us; speedup vs baseline: 1.9551x; 1.9551x over previous
//
#include <hip/hip_runtime.h>
#include <hip/hip_bf16.h>

// ---------------- problem constants ----------------
#define T_STEPS 16
#define BATCH   64
#define M_ROWS  1024          // T*B
#define K_DIM   60000
#define N1      200
#define N2      50
#define N3      2
#define NPAD    256           // W1 rows padded (rows 200..255 zero)
#define HN      (M_ROWS * N1) // 204800 elems per [m][n] slab

typedef __attribute__((ext_vector_type(8))) short    bf16x8;
typedef __attribute__((ext_vector_type(4))) float    f32x4;

// pack 8 f32 -> 8 bf16 via v_cvt_pk_bf16_f32 (compiler emits packed cvt)
static __device__ __forceinline__ bf16x8 cvt8(float4 lo, float4 hi) {
    union { bf16x8 v; __hip_bfloat162 h[4]; } u;
    u.h[0] = __float22bfloat162_rn(make_float2(lo.x, lo.y));
    u.h[1] = __float22bfloat162_rn(make_float2(lo.z, lo.w));
    u.h[2] = __float22bfloat162_rn(make_float2(hi.x, hi.y));
    u.h[3] = __float22bfloat162_rn(make_float2(hi.z, hi.w));
    return u.v;
}

// Kernel 0: W1 f32 -> bf16, padded to 256 rows (rows >=200 zero).
__global__ __launch_bounds__(256)
void cvt_w1(const float* __restrict__ w1, unsigned short* __restrict__ w1b) {
    const size_t e = ((size_t)blockIdx.x * 256 + threadIdx.x) * 8;
    if (e >= (size_t)NPAD * K_DIM) return;
    const int row = (int)(e / K_DIM);
    bf16x8 v = (bf16x8){0, 0, 0, 0, 0, 0, 0, 0};
    if (row < N1)
        v = cvt8(*(const float4*)(w1 + e), *(const float4*)(w1 + e + 4));
    *(bf16x8*)(w1b + e) = v;
}

// Kernel 1: part[s] = X[:, seg_s] @ W1b[:, seg_s].T  -- no LDS, no barriers.
// Block 256 = 4 waves; block tile 256m x 64n; wave tile 64m x 64n.
// D=2 circular register prefetch on both streams; packed f32->bf16 cvt.
template <int KSEG, int KSTEPS, int KSPLIT>
__global__ __launch_bounds__(256, 2)
void gemm_direct(const float* __restrict__ x,
                 const unsigned short* __restrict__ w1b,
                 float* __restrict__ part) {
    const int tid = threadIdx.x;
    const int l   = tid & 63;
    const int wv  = tid >> 6;

    // XCD-chunked swizzle (16*KSPLIT % 8 == 0 -> bijective): consecutive
    // logical ids (same s) land on one XCD so the W1b k-seg stays in its L2.
    const int hw      = blockIdx.y * 16 + blockIdx.x;
    const int chunk   = (16 * KSPLIT) / 8;
    const int logical = (hw & 7) * chunk + (hw >> 3);
    const int s  = logical >> 4;
    const int nt = (logical >> 2) & 3;
    const int mt = logical & 3;

    const int m0 = mt * 256 + wv * 64;
    const int n0 = nt * 64;
    const int k0 = s * KSEG;

    const int ra   = l & 15;               // fragment row
    const int koff = (l >> 4) * 8;         // fragment k-offset (elements)

    f32x4 acc[4][4];
    #pragma unroll
    for (int i = 0; i < 4; ++i)
        #pragma unroll
        for (int j = 0; j < 4; ++j) acc[i][j] = (f32x4){0.f, 0.f, 0.f, 0.f};

    const float* ax[4];
    const unsigned short* bx[4];
    #pragma unroll
    for (int fm = 0; fm < 4; ++fm)
        ax[fm] = x + (size_t)(m0 + fm * 16 + ra) * K_DIM + k0 + koff;
    #pragma unroll
    for (int fn = 0; fn < 4; ++fn)
        bx[fn] = w1b + (size_t)(n0 + fn * 16 + ra) * K_DIM + k0 + koff;

    // D=2 prefetch slots
    float4 a0[2][4], a1[2][4];
    bf16x8 bb[2][4];
    #pragma unroll
    for (int p = 0; p < 2; ++p) {
        const int off = p * 32;
        #pragma unroll
        for (int fm = 0; fm < 4; ++fm) {
            a0[p][fm] = *(const float4*)(ax[fm] + off);
            a1[p][fm] = *(const float4*)(ax[fm] + off + 4);
        }
        #pragma unroll
        for (int fn = 0; fn < 4; ++fn)
            bb[p][fn] = *(const bf16x8*)(bx[fn] + off);
    }

    #pragma unroll
    for (int it = 0; it < KSTEPS; ++it) {
        const int slot = it & 1;

        // consume slot: packed cvt A, snapshot B
        bf16x8 af[4], bf[4];
        #pragma unroll
        for (int fm = 0; fm < 4; ++fm) af[fm] = cvt8(a0[slot][fm], a1[slot][fm]);
        #pragma unroll
        for (int fn = 0; fn < 4; ++fn) bf[fn] = bb[slot][fn];

        // refill slot with it+2 (in flight across this iter's MFMA + next's)
        if (it + 2 < KSTEPS) {
            const int off = (it + 2) * 32;
            #pragma unroll
            for (int fm = 0; fm < 4; ++fm) {
                a0[slot][fm] = *(const float4*)(ax[fm] + off);
                a1[slot][fm] = *(const float4*)(ax[fm] + off + 4);
            }
            #pragma unroll
            for (int fn = 0; fn < 4; ++fn)
                bb[slot][fn] = *(const bf16x8*)(bx[fn] + off);
        }

        #pragma unroll
        for (int fn = 0; fn < 4; ++fn)
            #pragma unroll
            for (int fm = 0; fm < 4; ++fm)
                acc[fm][fn] = __builtin_amdgcn_mfma_f32_16x16x32_bf16(af[fm], bf[fn], acc[fm][fn], 0, 0, 0);
    }

    // epilogue: store cols < 200, part layout [s][m][n], ld = 200
    const int crow = (l >> 4) * 4;
    const int ccol = l & 15;
    #pragma unroll
    for (int fm = 0; fm < 4; ++fm)
        #pragma unroll
        for (int fn = 0; fn < 4; ++fn) {
            const int gn = n0 + fn * 16 + ccol;
            if (gn < N1) {
                const int gm = m0 + fm * 16 + crow;
                float* p = part + (size_t)s * HN + (size_t)gm * N1 + gn;
                #pragma unroll
                for (int r = 0; r < 4; ++r) p[(size_t)r * N1] = acc[fm][fn][r];
            }
        }
}

// Kernel 2: dense deterministic s-reduction: h1[f] = sum_s part[s][f]
// 800 blocks x 256 threads; KSPLIT independent loads per thread.
template <int KSPLIT>
__global__ __launch_bounds__(256)
void reduce_kernel(const float* __restrict__ part, float* __restrict__ h1) {
    const size_t f = (size_t)blockIdx.x * 256 + threadIdx.x;   // < 204800
    float v[KSPLIT];
    #pragma unroll
    for (int s = 0; s < KSPLIT; ++s) v[s] = part[(size_t)s * HN + f];
    float acc = 0.f;
    #pragma unroll
    for (int s = 0; s < KSPLIT; ++s) acc += v[s];
    h1[f] = acc;
}

// Kernel 3: fused LIF tail, latency-tolerant. One block per batch b.
// Phase 0: bulk-load w2/w3 -> LDS, h1(t=0..15) -> registers (independent).
// Phase 1: 16-step LIF-1 in registers, masks -> LDS.
// Phase 2: wave 0 runs layers 2-3 entirely from LDS/registers.
__global__ __launch_bounds__(256)
void tail_kernel(const float* __restrict__ h1,
                 const float* __restrict__ w2, const float* __restrict__ w3,
                 float* __restrict__ out) {
    __shared__ float w2s[N2 * N1];                  // 40 KB
    __shared__ float w3s[N3 * N2];                  // 400 B
    __shared__ unsigned long long msk[T_STEPS][4];  // 512 B

    const int b    = blockIdx.x;
    const int i    = threadIdx.x;
    const int wv   = i >> 6;
    const int lane = i & 63;

    // phase 0: cooperative loads (all independent, coalesced)
    for (int o = i; o < (N2 * N1) / 4; o += 256)
        ((float4*)w2s)[o] = ((const float4*)w2)[o];
    if (i < N3 * N2) w3s[i] = w3[i];

    float h[T_STEPS];
    #pragma unroll
    for (int t = 0; t < T_STEPS; ++t)
        h[t] = (i < N1) ? h1[(size_t)(t * BATCH + b) * N1 + i] : 0.f;

    // phase 1: LIF-1 recurrence (registers + ballot only)
    float v1 = 0.f;
    #pragma unroll
    for (int t = 0; t < T_STEPS; ++t) {
        v1 += (h[t] - v1) * 0.5f;
        bool sp = (v1 - 1.0f) >= 0.f;
        unsigned long long m = __ballot(sp);
        if (sp) v1 = 0.f;
        if (lane == 0) msk[t][wv] = m;
    }
    __syncthreads();

    // phase 2: layers 2+3, wave 0 only, LDS/VALU only
    if (wv == 0) {
        float v2 = 0.f, v3 = 0.f;
        for (int t = 0; t < T_STEPS; ++t) {
            float h2 = 0.f;
            if (lane < N2) {
                #pragma unroll
                for (int w = 0; w < 4; ++w) {
                    unsigned long long m = msk[t][w];
                    while (m) {
                        int lz = __builtin_ctzll(m);
                        m &= m - 1;
                        h2 += w2s[lane * N1 + (w * 64 + lz)];
                    }
                }
            }
            v2 += (h2 - v2) * 0.5f;
            bool sp2 = (v2 - 1.0f) >= 0.f;          // lanes >= 50: v2==0, false
            unsigned long long bal2 = __ballot(sp2);
            if (sp2) v2 = 0.f;

            float h3 = 0.f;
            if (lane < N3) {
                unsigned long long m = bal2;
                while (m) {
                    int j = __builtin_ctzll(m);
                    m &= m - 1;
                    h3 += w3s[lane * N2 + j];
                }
            }
            v3 += (h3 - v3) * 0.5f;
            bool sp3 = (v3 - 1.0f) >= 0.f;
            if (lane < N3)
                out[(size_t)(t * BATCH + b) * N3 + lane] = sp3 ? 1.f : 0.f;
            if (sp3) v3 = 0.f;
        }
    }
}

extern "C" void kernel_launch(void* const* d_in, const int* in_sizes, int n_in,
                              void* d_out, int out_size, void* d_ws, size_t ws_size,
                              hipStream_t stream) {
    const float* x  = (const float*)d_in[0];   // [16,64,150,400] -> [1024][60000]
    const float* w1 = (const float*)d_in[1];   // [200][60000]
    const float* w2 = (const float*)d_in[2];   // [50][200]
    const float* w3 = (const float*)d_in[3];   // [2][50]
    float* out = (float*)d_out;                // [16][64][2]

    const size_t w1b_bytes = (size_t)NPAD * K_DIM * 2;                 // 30.72 MB
    const size_t h1_bytes  = (size_t)HN * 4;                           // 0.82 MB
    const size_t need75 = (size_t)75 * HN * 4 + h1_bytes + w1b_bytes;  // 93 MB
    const bool big = ws_size >= need75;

    const int ksplit = big ? 75 : 25;
    float* part = (float*)d_ws;
    float* h1   = (float*)((char*)d_ws + (size_t)ksplit * HN * 4);
    unsigned short* w1b = (unsigned short*)((char*)h1 + h1_bytes);

    cvt_w1<<<7500, 256, 0, stream>>>(w1, w1b);
    if (big) {
        dim3 g(16, 75);
        gemm_direct<800, 25, 75><<<g, 256, 0, stream>>>(x, w1b, part);
        reduce_kernel<75><<<HN / 256, 256, 0, stream>>>(part, h1);
    } else {
        dim3 g(16, 25);
        gemm_direct<2400, 75, 25><<<g, 256, 0, stream>>>(x, w1b, part);
        reduce_kernel<25><<<HN / 256, 256, 0, stream>>>(part, h1);
    }
    tail_kernel<<<BATCH, 256, 0, stream>>>(h1, w2, w3, out);
}

// Round 6
// 151.775 us; speedup vs baseline: 3.2053x; 1.6394x over previous
//
#include <hip/hip_runtime.h>
#include <hip/hip_bf16.h>

// ---------------- problem constants ----------------
#define T_STEPS 16
#define BATCH   64
#define M_ROWS  1024          // T*B
#define K_DIM   60000
#define N1      200
#define N2      50
#define N3      2
#define NPAD    256           // W1 rows padded (rows 200..255 zero)
#define HN      (M_ROWS * N1) // 204800 elems per [m][n] slab

typedef __attribute__((ext_vector_type(8))) short    bf16x8;
typedef __attribute__((ext_vector_type(4))) float    f32x4;

// pack 8 f32 -> 8 bf16 (compiler emits v_cvt_pk_bf16_f32)
static __device__ __forceinline__ bf16x8 cvt8(float4 lo, float4 hi) {
    union { bf16x8 v; __hip_bfloat162 h[4]; } u;
    u.h[0] = __float22bfloat162_rn(make_float2(lo.x, lo.y));
    u.h[1] = __float22bfloat162_rn(make_float2(lo.z, lo.w));
    u.h[2] = __float22bfloat162_rn(make_float2(hi.x, hi.y));
    u.h[3] = __float22bfloat162_rn(make_float2(hi.z, hi.w));
    return u.v;
}

// async global->LDS, 16B per lane (dest = wave-uniform base + lane*16)
typedef __attribute__((address_space(3))) unsigned int       lds_u32;
typedef __attribute__((address_space(1))) const unsigned int glb_u32;
static __device__ __forceinline__ void gll16(const void* g, void* l) {
    __builtin_amdgcn_global_load_lds((glb_u32*)(unsigned long long)g,
                                     (lds_u32*)(unsigned int)(unsigned long long)l,
                                     16, 0, 0);
}

// Kernel 0: W1 f32 -> bf16, padded to 256 rows (rows >=200 zero).
__global__ __launch_bounds__(256)
void cvt_w1(const float* __restrict__ w1, unsigned short* __restrict__ w1b) {
    const size_t e = ((size_t)blockIdx.x * 256 + threadIdx.x) * 8;
    if (e >= (size_t)NPAD * K_DIM) return;
    const int row = (int)(e / K_DIM);
    bf16x8 v = (bf16x8){0, 0, 0, 0, 0, 0, 0, 0};
    if (row < N1)
        v = cvt8(*(const float4*)(w1 + e), *(const float4*)(w1 + e + 4));
    *(bf16x8*)(w1b + e) = v;
}

// Kernel 1: part[s] = X[:, seg_s] @ W1b[:, seg_s].T
// Block: 64m x 256n, BK=32, 4 waves (wave wv owns n-cols [wv*64, wv*64+64)).
// 2-phase double-buffered global_load_lds pipeline (T3-minimum):
//   STAGE(next buf) ; ds_read+cvt+MFMA(cur buf) ; vmcnt(0)+barrier.
// LDS buf (24KB): A = [64 rows][128B f32] (XOR-swizzled granules, via
// pre-swizzled global source), then B = [256 rows][64B bf16] (no swizzle:
// 64B row stride is naturally bank-spread).
template <int KSEG, int KSTEPS, int NWG>
__global__ __launch_bounds__(256, 3)
void gemm_lds(const float* __restrict__ x,
              const unsigned short* __restrict__ w1b,
              float* __restrict__ part) {
    __shared__ __align__(16) char smem[2][24576];

    const int tid = threadIdx.x;
    const int l   = tid & 63;
    const int wv  = tid >> 6;

    // bijective XCD-chunked swizzle (NWG % 8 == 0): the 16 blocks sharing a
    // k-segment (same s) land on one XCD -> W1b segment stays in its L2.
    const int hw      = blockIdx.y * 16 + blockIdx.x;
    const int logical = (hw & 7) * (NWG / 8) + (hw >> 3);
    const int s  = logical >> 4;
    const int mt = logical & 15;

    const int m0 = mt * 64;
    const int k0 = s * KSEG;

    // ---- staging assignment: 24 chunks of 1KB; chunk c -> LDS [c*1024).
    // c in 0..7  : A chunk, rows c*8 + (l>>3), granule 16*((l&7)^(l>>3))
    //              of the 128B row window (pre-swizzled source).
    // c in 8..23 : B chunk, rows (c-8)*16 + (l>>2), bytes (l&3)*16 of 64B row.
    const char* gsrc[6];
    int         gstp[6];
    int         loff[6];
    #pragma unroll
    for (int j = 0; j < 6; ++j) {
        const int c = wv * 6 + j;
        loff[j] = c * 1024 + l * 16;
        if (c < 8) {
            const int row = c * 8 + (l >> 3);
            gsrc[j] = (const char*)(x + (size_t)(m0 + row) * K_DIM + k0)
                      + 16 * ((l & 7) ^ (l >> 3));
            gstp[j] = 32 * 4;            // BK floats
        } else {
            const int row = (c - 8) * 16 + (l >> 2);
            gsrc[j] = (const char*)(w1b + (size_t)row * K_DIM + k0)
                      + (l & 3) * 16;
            gstp[j] = 32 * 2;            // BK bf16
        }
    }

    f32x4 acc[4][4];
    #pragma unroll
    for (int i = 0; i < 4; ++i)
        #pragma unroll
        for (int j = 0; j < 4; ++j) acc[i][j] = (f32x4){0.f, 0.f, 0.f, 0.f};

    // prologue: stage step 0 into buf 0
    #pragma unroll
    for (int j = 0; j < 6; ++j) gll16(gsrc[j], smem[0] + loff[j]);
    asm volatile("s_waitcnt vmcnt(0)" ::: "memory");
    __syncthreads();

    const int ra = l & 15;        // fragment row
    const int kq = l >> 4;        // k-quarter (8 elems each)

    for (int it = 0; it < KSTEPS; ++it) {
        const int cur = it & 1;

        // phase 1: issue async stage of step it+1 into the other buffer
        if (it + 1 < KSTEPS) {
            #pragma unroll
            for (int j = 0; j < 6; ++j)
                gll16(gsrc[j] + (size_t)(it + 1) * gstp[j], smem[cur ^ 1] + loff[j]);
        }

        // phase 2: compute on buf[cur]
        const char* ab = smem[cur];
        const char* bb = smem[cur] + 8192;

        bf16x8 af[4];
        #pragma unroll
        for (int fm = 0; fm < 4; ++fm) {
            const int r  = fm * 16 + ra;
            const int sw = (r & 7) << 4;
            const char* rp = ab + r * 128;
            float4 lo = *(const float4*)(rp + ((kq * 32) ^ sw));
            float4 hi = *(const float4*)(rp + ((kq * 32 + 16) ^ sw));
            af[fm] = cvt8(lo, hi);
        }
        #pragma unroll
        for (int fn = 0; fn < 4; ++fn) {
            const int n = wv * 64 + fn * 16 + ra;
            bf16x8 bf = *(const bf16x8*)(bb + n * 64 + kq * 16);
            #pragma unroll
            for (int fm = 0; fm < 4; ++fm)
                acc[fm][fn] = __builtin_amdgcn_mfma_f32_16x16x32_bf16(af[fm], bf, acc[fm][fn], 0, 0, 0);
        }

        // phase 3: drain staged loads + barrier (one barrier per step)
        asm volatile("s_waitcnt vmcnt(0)" ::: "memory");
        __syncthreads();
    }

    // epilogue: store cols < 200, part layout [s][m][n], ld = 200
    const int crow = (l >> 4) * 4;
    const int ccol = l & 15;
    #pragma unroll
    for (int fm = 0; fm < 4; ++fm)
        #pragma unroll
        for (int fn = 0; fn < 4; ++fn) {
            const int gn = wv * 64 + fn * 16 + ccol;
            if (gn < N1) {
                const int gm = m0 + fm * 16 + crow;
                float* p = part + (size_t)s * HN + (size_t)gm * N1 + gn;
                #pragma unroll
                for (int r = 0; r < 4; ++r) p[(size_t)r * N1] = acc[fm][fn][r];
            }
        }
}

// Kernel 2: dense deterministic s-reduction: h1[f] = sum_s part[s][f]
template <int KSPLIT>
__global__ __launch_bounds__(256)
void reduce_kernel(const float* __restrict__ part, float* __restrict__ h1) {
    const size_t f = (size_t)blockIdx.x * 256 + threadIdx.x;   // < 204800
    float v[KSPLIT];
    #pragma unroll
    for (int s = 0; s < KSPLIT; ++s) v[s] = part[(size_t)s * HN + f];
    float acc = 0.f;
    #pragma unroll
    for (int s = 0; s < KSPLIT; ++s) acc += v[s];
    h1[f] = acc;
}

// Kernel 3: fused LIF tail, latency-tolerant. One block per batch b.
__global__ __launch_bounds__(256)
void tail_kernel(const float* __restrict__ h1,
                 const float* __restrict__ w2, const float* __restrict__ w3,
                 float* __restrict__ out) {
    __shared__ float w2s[N2 * N1];                  // 40 KB
    __shared__ float w3s[N3 * N2];
    __shared__ unsigned long long msk[T_STEPS][4];

    const int b    = blockIdx.x;
    const int i    = threadIdx.x;
    const int wv   = i >> 6;
    const int lane = i & 63;

    for (int o = i; o < (N2 * N1) / 4; o += 256)
        ((float4*)w2s)[o] = ((const float4*)w2)[o];
    if (i < N3 * N2) w3s[i] = w3[i];

    float h[T_STEPS];
    #pragma unroll
    for (int t = 0; t < T_STEPS; ++t)
        h[t] = (i < N1) ? h1[(size_t)(t * BATCH + b) * N1 + i] : 0.f;

    float v1 = 0.f;
    #pragma unroll
    for (int t = 0; t < T_STEPS; ++t) {
        v1 += (h[t] - v1) * 0.5f;
        bool sp = (v1 - 1.0f) >= 0.f;
        unsigned long long m = __ballot(sp);
        if (sp) v1 = 0.f;
        if (lane == 0) msk[t][wv] = m;
    }
    __syncthreads();

    if (wv == 0) {
        float v2 = 0.f, v3 = 0.f;
        for (int t = 0; t < T_STEPS; ++t) {
            float h2 = 0.f;
            if (lane < N2) {
                #pragma unroll
                for (int w = 0; w < 4; ++w) {
                    unsigned long long m = msk[t][w];
                    while (m) {
                        int lz = __builtin_ctzll(m);
                        m &= m - 1;
                        h2 += w2s[lane * N1 + (w * 64 + lz)];
                    }
                }
            }
            v2 += (h2 - v2) * 0.5f;
            bool sp2 = (v2 - 1.0f) >= 0.f;
            unsigned long long bal2 = __ballot(sp2);
            if (sp2) v2 = 0.f;

            float h3 = 0.f;
            if (lane < N3) {
                unsigned long long m = bal2;
                while (m) {
                    int j = __builtin_ctzll(m);
                    m &= m - 1;
                    h3 += w3s[lane * N2 + j];
                }
            }
            v3 += (h3 - v3) * 0.5f;
            bool sp3 = (v3 - 1.0f) >= 0.f;
            if (lane < N3)
                out[(size_t)(t * BATCH + b) * N3 + lane] = sp3 ? 1.f : 0.f;
            if (sp3) v3 = 0.f;
        }
    }
}

extern "C" void kernel_launch(void* const* d_in, const int* in_sizes, int n_in,
                              void* d_out, int out_size, void* d_ws, size_t ws_size,
                              hipStream_t stream) {
    const float* x  = (const float*)d_in[0];   // [16,64,150,400] -> [1024][60000]
    const float* w1 = (const float*)d_in[1];   // [200][60000]
    const float* w2 = (const float*)d_in[2];   // [50][200]
    const float* w3 = (const float*)d_in[3];   // [2][50]
    float* out = (float*)d_out;                // [16][64][2]

    const size_t w1b_bytes = (size_t)NPAD * K_DIM * 2;                 // 30.72 MB
    const size_t h1_bytes  = (size_t)HN * 4;                           // 0.82 MB
    const size_t need75 = (size_t)75 * HN * 4 + h1_bytes + w1b_bytes;  // 93 MB
    const bool big = ws_size >= need75;

    const int ksplit = big ? 75 : 25;
    float* part = (float*)d_ws;
    float* h1   = (float*)((char*)d_ws + (size_t)ksplit * HN * 4);
    unsigned short* w1b = (unsigned short*)((char*)h1 + h1_bytes);

    cvt_w1<<<7500, 256, 0, stream>>>(w1, w1b);
    if (big) {
        dim3 g(16, 75);
        gemm_lds<800, 25, 1200><<<g, 256, 0, stream>>>(x, w1b, part);
        reduce_kernel<75><<<HN / 256, 256, 0, stream>>>(part, h1);
    } else {
        dim3 g(16, 25);
        gemm_lds<2400, 75, 400><<<g, 256, 0, stream>>>(x, w1b, part);
        reduce_kernel<25><<<HN / 256, 256, 0, stream>>>(part, h1);
    }
    tail_kernel<<<BATCH, 256, 0, stream>>>(h1, w2, w3, out);
}

// Round 7
// 144.494 us; speedup vs baseline: 3.3669x; 1.0504x over previous
//
#include <hip/hip_runtime.h>
#include <hip/hip_bf16.h>

// ---------------- problem constants ----------------
#define T_STEPS 16
#define BATCH   64
#define M_ROWS  1024          // T*B
#define K_DIM   60000
#define N1      200
#define N2      50
#define N3      2
#define NPAD    256           // W1 rows padded (rows 200..255 zero)
#define HN      (M_ROWS * N1) // 204800 elems per [m][n] slab
#define BK      32            // k per step

typedef __attribute__((ext_vector_type(8))) short    bf16x8;
typedef __attribute__((ext_vector_type(4))) float    f32x4;

// pack 8 f32 -> 8 bf16 (compiler emits v_cvt_pk_bf16_f32)
static __device__ __forceinline__ bf16x8 cvt8(float4 lo, float4 hi) {
    union { bf16x8 v; __hip_bfloat162 h[4]; } u;
    u.h[0] = __float22bfloat162_rn(make_float2(lo.x, lo.y));
    u.h[1] = __float22bfloat162_rn(make_float2(lo.z, lo.w));
    u.h[2] = __float22bfloat162_rn(make_float2(hi.x, hi.y));
    u.h[3] = __float22bfloat162_rn(make_float2(hi.z, hi.w));
    return u.v;
}

// async global->LDS, 16B per lane (dest = wave-uniform base + lane*16)
typedef __attribute__((address_space(3))) unsigned int       lds_u32;
typedef __attribute__((address_space(1))) const unsigned int glb_u32;
static __device__ __forceinline__ void gll16(const void* g, void* l) {
    __builtin_amdgcn_global_load_lds((glb_u32*)(unsigned long long)g,
                                     (lds_u32*)(unsigned int)(unsigned long long)l,
                                     16, 0, 0);
}

// Kernel 0: W1 f32 -> bf16, padded to 256 rows (rows >=200 zero).
__global__ __launch_bounds__(256)
void cvt_w1(const float* __restrict__ w1, unsigned short* __restrict__ w1b) {
    const size_t e = ((size_t)blockIdx.x * 256 + threadIdx.x) * 8;
    if (e >= (size_t)NPAD * K_DIM) return;
    const int row = (int)(e / K_DIM);
    bf16x8 v = (bf16x8){0, 0, 0, 0, 0, 0, 0, 0};
    if (row < N1)
        v = cvt8(*(const float4*)(w1 + e), *(const float4*)(w1 + e + 4));
    *(bf16x8*)(w1b + e) = v;
}

// Kernel 1: part[s] = X[:, seg_s] @ W1b[:, seg_s].T
// Block 64m x 256n, BK=32, 4 waves (wave wv owns n-cols [wv*64, wv*64+64)).
// Double-buffered 2-phase pipeline:
//   A: global f32 -> regs (T14 issue-early) -> cvt_pk bf16 -> swizzled ds_write
//   B: global_load_lds (bf16), source pre-swizzled
//   both tiles stored as [rows][64B], granule-XOR swizzle p = g ^ ((row>>1)&3)
//   -> every ds_read/ds_write slot pattern is 2 lanes/16B-slot (free, m136).
// LDS 2 x 20KB = 40KB -> 4 blocks/CU.
template <int KSEG, int KSTEPS, int NWG>
__global__ __launch_bounds__(256, 4)
void gemm_lds(const float* __restrict__ x,
              const unsigned short* __restrict__ w1b,
              float* __restrict__ part) {
    __shared__ __align__(16) char smem[2][20480];   // [A 4KB][B 16KB] per buf

    const int tid = threadIdx.x;
    const int l   = tid & 63;
    const int wv  = tid >> 6;

    // bijective XCD-chunked swizzle (NWG % 8 == 0): the 16 blocks sharing a
    // k-segment (same s) land on one XCD -> W1b segment stays in its L2.
    const int hw      = blockIdx.y * 16 + blockIdx.x;
    const int logical = (hw & 7) * (NWG / 8) + (hw >> 3);
    const int s  = logical >> 4;
    const int mt = logical & 15;

    const int m0 = mt * 64;
    const int k0 = s * KSEG;

    // ---- A reg-staging assignment: thread -> (row, 8-float granule) ----
    const int ar = tid >> 2;                 // 0..63 row
    const int ag = tid & 3;                  // granule (8 floats / 8 bf16)
    const float* asrc = x + (size_t)(m0 + ar) * K_DIM + k0 + ag * 8;
    const int aw_off = ar * 64 + ((ag ^ ((ar >> 1) & 3)) << 4);  // swizzled write

    // ---- B gll16 assignment: 4 chunks of 1KB per thread ----
    const char* bsrc[4];
    int         bl_off[4];
    #pragma unroll
    for (int j = 0; j < 4; ++j) {
        const int c   = wv * 4 + j;          // chunk 0..15
        const int row = c * 16 + (l >> 2);
        bl_off[j] = 4096 + c * 1024 + l * 16;            // linear LDS dest
        bsrc[j]   = (const char*)(w1b + (size_t)row * K_DIM + k0)
                    + (((l & 3) ^ ((row >> 1) & 3)) << 4);  // pre-swizzled src
    }

    f32x4 acc[4][4];
    #pragma unroll
    for (int i = 0; i < 4; ++i)
        #pragma unroll
        for (int j = 0; j < 4; ++j) acc[i][j] = (f32x4){0.f, 0.f, 0.f, 0.f};

    // ---- prologue: stage step 0 into buf 0 ----
    float4 a0 = *(const float4*)asrc;
    float4 a1 = *(const float4*)(asrc + 4);
    #pragma unroll
    for (int j = 0; j < 4; ++j) gll16(bsrc[j], smem[0] + bl_off[j]);
    *(bf16x8*)(smem[0] + aw_off) = cvt8(a0, a1);
    asm volatile("s_waitcnt vmcnt(0)" ::: "memory");
    __syncthreads();

    const int ra = l & 15;        // fragment row
    const int kq = l >> 4;        // fragment k-granule

    for (int it = 0; it < KSTEPS; ++it) {
        const int cur = it & 1;

        // issue-early: next step's A regs + B gll16 into the other buffer
        if (it + 1 < KSTEPS) {
            const int off = (it + 1) * BK;
            a0 = *(const float4*)(asrc + off);
            a1 = *(const float4*)(asrc + off + 4);
            #pragma unroll
            for (int j = 0; j < 4; ++j)
                gll16(bsrc[j] + (size_t)(it + 1) * (BK * 2), smem[cur ^ 1] + bl_off[j]);
        }

        // compute on buf[cur]
        const char* ab = smem[cur];
        const char* bb = smem[cur] + 4096;
        bf16x8 af[4];
        #pragma unroll
        for (int fm = 0; fm < 4; ++fm) {
            const int r = fm * 16 + ra;
            af[fm] = *(const bf16x8*)(ab + r * 64 + ((kq * 16) ^ (((r >> 1) & 3) << 4)));
        }
        #pragma unroll
        for (int fn = 0; fn < 4; ++fn) {
            const int n = wv * 64 + fn * 16 + ra;
            bf16x8 bfv = *(const bf16x8*)(bb + n * 64 + ((kq * 16) ^ (((n >> 1) & 3) << 4)));
            #pragma unroll
            for (int fm = 0; fm < 4; ++fm)
                acc[fm][fn] = __builtin_amdgcn_mfma_f32_16x16x32_bf16(af[fm], bfv, acc[fm][fn], 0, 0, 0);
        }

        // write-late: cvt + swizzled ds_write of next A into buf[cur^1]
        if (it + 1 < KSTEPS)
            *(bf16x8*)(smem[cur ^ 1] + aw_off) = cvt8(a0, a1);

        // drain B stage + step barrier (ds_writes drained by syncthreads' lgkm)
        asm volatile("s_waitcnt vmcnt(0)" ::: "memory");
        __syncthreads();
    }

    // epilogue: store cols < 200, part layout [s][m][n], ld = 200
    const int crow = (l >> 4) * 4;
    const int ccol = l & 15;
    #pragma unroll
    for (int fm = 0; fm < 4; ++fm)
        #pragma unroll
        for (int fn = 0; fn < 4; ++fn) {
            const int gn = wv * 64 + fn * 16 + ccol;
            if (gn < N1) {
                const int gm = m0 + fm * 16 + crow;
                float* p = part + (size_t)s * HN + (size_t)gm * N1 + gn;
                #pragma unroll
                for (int r = 0; r < 4; ++r) p[(size_t)r * N1] = acc[fm][fn][r];
            }
        }
}

// Kernel 2: dense deterministic s-reduction: h1[f] = sum_s part[s][f]
template <int KSPLIT>
__global__ __launch_bounds__(256)
void reduce_kernel(const float* __restrict__ part, float* __restrict__ h1) {
    const size_t f = (size_t)blockIdx.x * 256 + threadIdx.x;   // < 204800
    float v[KSPLIT];
    #pragma unroll
    for (int s = 0; s < KSPLIT; ++s) v[s] = part[(size_t)s * HN + f];
    float acc = 0.f;
    #pragma unroll
    for (int s = 0; s < KSPLIT; ++s) acc += v[s];
    h1[f] = acc;
}

// Kernel 3: fused LIF tail, latency-tolerant. One block per batch b.
__global__ __launch_bounds__(256)
void tail_kernel(const float* __restrict__ h1,
                 const float* __restrict__ w2, const float* __restrict__ w3,
                 float* __restrict__ out) {
    __shared__ float w2s[N2 * N1];                  // 40 KB
    __shared__ float w3s[N3 * N2];
    __shared__ unsigned long long msk[T_STEPS][4];

    const int b    = blockIdx.x;
    const int i    = threadIdx.x;
    const int wv   = i >> 6;
    const int lane = i & 63;

    for (int o = i; o < (N2 * N1) / 4; o += 256)
        ((float4*)w2s)[o] = ((const float4*)w2)[o];
    if (i < N3 * N2) w3s[i] = w3[i];

    float h[T_STEPS];
    #pragma unroll
    for (int t = 0; t < T_STEPS; ++t)
        h[t] = (i < N1) ? h1[(size_t)(t * BATCH + b) * N1 + i] : 0.f;

    float v1 = 0.f;
    #pragma unroll
    for (int t = 0; t < T_STEPS; ++t) {
        v1 += (h[t] - v1) * 0.5f;
        bool sp = (v1 - 1.0f) >= 0.f;
        unsigned long long m = __ballot(sp);
        if (sp) v1 = 0.f;
        if (lane == 0) msk[t][wv] = m;
    }
    __syncthreads();

    if (wv == 0) {
        float v2 = 0.f, v3 = 0.f;
        for (int t = 0; t < T_STEPS; ++t) {
            float h2 = 0.f;
            if (lane < N2) {
                #pragma unroll
                for (int w = 0; w < 4; ++w) {
                    unsigned long long m = msk[t][w];
                    while (m) {
                        int lz = __builtin_ctzll(m);
                        m &= m - 1;
                        h2 += w2s[lane * N1 + (w * 64 + lz)];
                    }
                }
            }
            v2 += (h2 - v2) * 0.5f;
            bool sp2 = (v2 - 1.0f) >= 0.f;
            unsigned long long bal2 = __ballot(sp2);
            if (sp2) v2 = 0.f;

            float h3 = 0.f;
            if (lane < N3) {
                unsigned long long m = bal2;
                while (m) {
                    int j = __builtin_ctzll(m);
                    m &= m - 1;
                    h3 += w3s[lane * N2 + j];
                }
            }
            v3 += (h3 - v3) * 0.5f;
            bool sp3 = (v3 - 1.0f) >= 0.f;
            if (lane < N3)
                out[(size_t)(t * BATCH + b) * N3 + lane] = sp3 ? 1.f : 0.f;
            if (sp3) v3 = 0.f;
        }
    }
}

extern "C" void kernel_launch(void* const* d_in, const int* in_sizes, int n_in,
                              void* d_out, int out_size, void* d_ws, size_t ws_size,
                              hipStream_t stream) {
    const float* x  = (const float*)d_in[0];   // [16,64,150,400] -> [1024][60000]
    const float* w1 = (const float*)d_in[1];   // [200][60000]
    const float* w2 = (const float*)d_in[2];   // [50][200]
    const float* w3 = (const float*)d_in[3];   // [2][50]
    float* out = (float*)d_out;                // [16][64][2]

    const size_t w1b_bytes = (size_t)NPAD * K_DIM * 2;                 // 30.72 MB
    const size_t h1_bytes  = (size_t)HN * 4;                           // 0.82 MB
    const size_t need75 = (size_t)75 * HN * 4 + h1_bytes + w1b_bytes;  // 93 MB
    const bool big = ws_size >= need75;

    const int ksplit = big ? 75 : 25;
    float* part = (float*)d_ws;
    float* h1   = (float*)((char*)d_ws + (size_t)ksplit * HN * 4);
    unsigned short* w1b = (unsigned short*)((char*)h1 + h1_bytes);

    cvt_w1<<<7500, 256, 0, stream>>>(w1, w1b);
    if (big) {
        dim3 g(16, 75);
        gemm_lds<800, 25, 1200><<<g, 256, 0, stream>>>(x, w1b, part);
        reduce_kernel<75><<<HN / 256, 256, 0, stream>>>(part, h1);
    } else {
        dim3 g(16, 25);
        gemm_lds<2400, 75, 400><<<g, 256, 0, stream>>>(x, w1b, part);
        reduce_kernel<25><<<HN / 256, 256, 0, stream>>>(part, h1);
    }
    tail_kernel<<<BATCH, 256, 0, stream>>>(h1, w2, w3, out);
}

// Round 8
// 136.138 us; speedup vs baseline: 3.5735x; 1.0614x over previous
//
#include <hip/hip_runtime.h>
#include <hip/hip_bf16.h>

// ---------------- problem constants ----------------
#define T_STEPS 16
#define BATCH   64
#define M_ROWS  1024          // T*B
#define K_DIM   60000
#define N1      200
#define N2      50
#define N3      2
#define NPAD    256           // w1b allocated rows (200..255 never written: junk only feeds unstored acc cols)
#define HN      (M_ROWS * N1) // 204800 elems per [m][n] slab
#define BK      32            // k per step

typedef __attribute__((ext_vector_type(8))) short    bf16x8;
typedef __attribute__((ext_vector_type(4))) float    f32x4;

// pack 8 f32 -> 8 bf16 (compiler emits v_cvt_pk_bf16_f32)
static __device__ __forceinline__ bf16x8 cvt8(float4 lo, float4 hi) {
    union { bf16x8 v; __hip_bfloat162 h[4]; } u;
    u.h[0] = __float22bfloat162_rn(make_float2(lo.x, lo.y));
    u.h[1] = __float22bfloat162_rn(make_float2(lo.z, lo.w));
    u.h[2] = __float22bfloat162_rn(make_float2(hi.x, hi.y));
    u.h[3] = __float22bfloat162_rn(make_float2(hi.z, hi.w));
    return u.v;
}

static __device__ __forceinline__ float bf2f(unsigned short u) {
    unsigned int x = (unsigned int)u << 16;
    return __uint_as_float(x);
}

// async global->LDS, 16B per lane (dest = wave-uniform base + lane*16)
typedef __attribute__((address_space(3))) unsigned int       lds_u32;
typedef __attribute__((address_space(1))) const unsigned int glb_u32;
static __device__ __forceinline__ void gll16(const void* g, void* l) {
    __builtin_amdgcn_global_load_lds((glb_u32*)(unsigned long long)g,
                                     (lds_u32*)(unsigned int)(unsigned long long)l,
                                     16, 0, 0);
}

// Kernel 0: W1 f32 -> bf16 (rows < 200 only; rows 200..255 stay junk -- they
// only ever multiply into acc columns gn >= 200, which are never stored).
__global__ __launch_bounds__(256)
void cvt_w1(const float* __restrict__ w1, unsigned short* __restrict__ w1b) {
    const size_t e = ((size_t)blockIdx.x * 256 + threadIdx.x) * 8;
    if (e >= (size_t)N1 * K_DIM) return;
    *(bf16x8*)(w1b + e) = cvt8(*(const float4*)(w1 + e),
                               *(const float4*)(w1 + e + 4));
}

// Kernel 1: part[s] = X[:, seg_s] @ W1b[:, seg_s].T   (bf16 partials out)
// Block 64m x 256n, BK=32, 4 waves (wave wv owns n-cols [wv*64, wv*64+64)).
// T4-counted double-buffered pipeline, fully unrolled (static slot indexing):
//   per iter: [issue B(it+1) gll16 -> buf^1 ; issue A(it+2) -> reg slot]
//             SCHED_BARRIER
//             [ds_read + MFMA on buf ; cvt A(it+1) -> swizzled ds_write buf^1]
//             SCHED_BARRIER ; s_waitcnt vmcnt(2) ; s_barrier
// vmcnt(2): B issued before A each iter; in-order retirement => <=2 outstanding
// (the A(it+2) pair) implies B(it+1) landed. Queue never drains to 0.
// A regs are 2-deep => ~2-step (~1000 cyc) HBM latency tolerance.
// Swizzle (both tiles [row][64B], granule-XOR p = g ^ ((row>>1)&3)): A write
// and A/B reads use the same involution; B applied via pre-swizzled source.
template <int KSEG, int KSTEPS, int NWG>
__global__ __launch_bounds__(256, 4)
void gemm_lds(const float* __restrict__ x,
              const unsigned short* __restrict__ w1b,
              unsigned short* __restrict__ part) {
    __shared__ __align__(16) char smem[2][20480];   // [A 4KB][B 16KB] per buf

    const int tid = threadIdx.x;
    const int l   = tid & 63;
    const int wv  = tid >> 6;

    // bijective XCD-chunked swizzle (NWG % 8 == 0): 16 blocks sharing a
    // k-segment land on one XCD -> W1b segment stays in that L2.
    const int hw      = blockIdx.y * 16 + blockIdx.x;
    const int logical = (hw & 7) * (NWG / 8) + (hw >> 3);
    const int s  = logical >> 4;
    const int mt = logical & 15;

    const int m0 = mt * 64;
    const int k0 = s * KSEG;

    // A reg-staging: thread -> (row ar, 8-float granule ag)
    const int ar = tid >> 2;
    const int ag = tid & 3;
    const float* asrc = x + (size_t)(m0 + ar) * K_DIM + k0 + ag * 8;
    const int aw_off = ar * 64 + ((ag ^ ((ar >> 1) & 3)) << 4);

    // B gll16: 4 chunks of 1KB per thread, linear LDS dest, pre-swizzled src
    const char* bsrc[4];
    int         bl_off[4];
    #pragma unroll
    for (int j = 0; j < 4; ++j) {
        const int c   = wv * 4 + j;
        const int row = c * 16 + (l >> 2);
        bl_off[j] = 4096 + c * 1024 + l * 16;
        bsrc[j]   = (const char*)(w1b + (size_t)row * K_DIM + k0)
                    + (((l & 3) ^ ((row >> 1) & 3)) << 4);
    }

    f32x4 acc[4][4];
    #pragma unroll
    for (int i = 0; i < 4; ++i)
        #pragma unroll
        for (int j = 0; j < 4; ++j) acc[i][j] = (f32x4){0.f, 0.f, 0.f, 0.f};

    // ---- prologue: B(0) first, then A(0), A(1) (issue order matters) ----
    float4 p0[2], p1[2];                   // A reg slots, index = step parity
    #pragma unroll
    for (int j = 0; j < 4; ++j) gll16(bsrc[j], smem[0] + bl_off[j]);
    p0[0] = *(const float4*)asrc;
    p1[0] = *(const float4*)(asrc + 4);
    p0[1] = *(const float4*)(asrc + BK);
    p1[1] = *(const float4*)(asrc + BK + 4);
    *(bf16x8*)(smem[0] + aw_off) = cvt8(p0[0], p1[0]);
    __builtin_amdgcn_sched_barrier(0);
    asm volatile("s_waitcnt vmcnt(2)" ::: "memory");   // B(0) done; A(1) may fly
    __syncthreads();

    const int ra = l & 15;        // fragment row
    const int kq = l >> 4;        // fragment k-granule

    #pragma unroll
    for (int it = 0; it < KSTEPS; ++it) {
        const int cur = it & 1;
        const bool more = (it + 1) < KSTEPS;

        // phase 1: issue next B (gll16, first) and A(it+2) (regs, second)
        if (more) {
            #pragma unroll
            for (int j = 0; j < 4; ++j)
                gll16(bsrc[j] + (size_t)(it + 1) * (BK * 2), smem[cur ^ 1] + bl_off[j]);
            const int jn = (it + 2 < KSTEPS) ? (it + 2) : (KSTEPS - 1);
            p0[cur] = *(const float4*)(asrc + jn * BK);       // slot (it+2)&1 == cur
            p1[cur] = *(const float4*)(asrc + jn * BK + 4);
        }
        __builtin_amdgcn_sched_barrier(0);

        // phase 2: compute on buf[cur]
        const char* ab = smem[cur];
        const char* bb = smem[cur] + 4096;
        bf16x8 af[4];
        #pragma unroll
        for (int fm = 0; fm < 4; ++fm) {
            const int r = fm * 16 + ra;
            af[fm] = *(const bf16x8*)(ab + r * 64 + ((kq * 16) ^ (((r >> 1) & 3) << 4)));
        }
        #pragma unroll
        for (int fn = 0; fn < 4; ++fn) {
            const int n = wv * 64 + fn * 16 + ra;
            bf16x8 bfv = *(const bf16x8*)(bb + n * 64 + ((kq * 16) ^ (((n >> 1) & 3) << 4)));
            #pragma unroll
            for (int fm = 0; fm < 4; ++fm)
                acc[fm][fn] = __builtin_amdgcn_mfma_f32_16x16x32_bf16(af[fm], bfv, acc[fm][fn], 0, 0, 0);
        }

        // write-late: cvt A(it+1) (slot cur^1) -> swizzled ds_write into buf^1
        if (more) {
            *(bf16x8*)(smem[cur ^ 1] + aw_off) = cvt8(p0[cur ^ 1], p1[cur ^ 1]);
            __builtin_amdgcn_sched_barrier(0);
            asm volatile("s_waitcnt vmcnt(2)" ::: "memory");  // B(it+1) done
            __syncthreads();
        }
    }

    // epilogue: store cols < 200 as bf16, part layout [s][m][n], ld = 200
    const int crow = (l >> 4) * 4;
    const int ccol = l & 15;
    #pragma unroll
    for (int fm = 0; fm < 4; ++fm)
        #pragma unroll
        for (int fn = 0; fn < 4; ++fn) {
            const int gn = wv * 64 + fn * 16 + ccol;
            if (gn < N1) {
                const int gm = m0 + fm * 16 + crow;
                unsigned short* p = part + (size_t)s * HN + (size_t)gm * N1 + gn;
                #pragma unroll
                for (int r = 0; r < 4; ++r) {
                    __hip_bfloat16 hv = __float2bfloat16(acc[fm][fn][r]);
                    p[(size_t)r * N1] = *(unsigned short*)&hv;
                }
            }
        }
}

// Kernel 2: dense deterministic s-reduction of bf16 partials -> f32 h1.
// Thread handles 2 adjacent elems (u32 loads); KSPLIT independent loads each.
template <int KSPLIT>
__global__ __launch_bounds__(256)
void reduce_kernel(const unsigned short* __restrict__ part, float* __restrict__ h1) {
    const size_t f = ((size_t)blockIdx.x * 256 + threadIdx.x) * 2;   // < 204800
    float a0 = 0.f, a1 = 0.f;
    #pragma unroll
    for (int s = 0; s < KSPLIT; ++s) {
        const unsigned int v = *(const unsigned int*)(part + (size_t)s * HN + f);
        a0 += bf2f((unsigned short)(v & 0xFFFFu));
        a1 += bf2f((unsigned short)(v >> 16));
    }
    h1[f]     = a0;
    h1[f + 1] = a1;
}

// Kernel 3: fused LIF tail, latency-tolerant. One block per batch b.
__global__ __launch_bounds__(256)
void tail_kernel(const float* __restrict__ h1,
                 const float* __restrict__ w2, const float* __restrict__ w3,
                 float* __restrict__ out) {
    __shared__ float w2s[N2 * N1];                  // 40 KB
    __shared__ float w3s[N3 * N2];
    __shared__ unsigned long long msk[T_STEPS][4];

    const int b    = blockIdx.x;
    const int i    = threadIdx.x;
    const int wv   = i >> 6;
    const int lane = i & 63;

    for (int o = i; o < (N2 * N1) / 4; o += 256)
        ((float4*)w2s)[o] = ((const float4*)w2)[o];
    if (i < N3 * N2) w3s[i] = w3[i];

    float h[T_STEPS];
    #pragma unroll
    for (int t = 0; t < T_STEPS; ++t)
        h[t] = (i < N1) ? h1[(size_t)(t * BATCH + b) * N1 + i] : 0.f;

    float v1 = 0.f;
    #pragma unroll
    for (int t = 0; t < T_STEPS; ++t) {
        v1 += (h[t] - v1) * 0.5f;
        bool sp = (v1 - 1.0f) >= 0.f;
        unsigned long long m = __ballot(sp);
        if (sp) v1 = 0.f;
        if (lane == 0) msk[t][wv] = m;
    }
    __syncthreads();

    if (wv == 0) {
        float v2 = 0.f, v3 = 0.f;
        for (int t = 0; t < T_STEPS; ++t) {
            float h2 = 0.f;
            if (lane < N2) {
                #pragma unroll
                for (int w = 0; w < 4; ++w) {
                    unsigned long long m = msk[t][w];
                    while (m) {
                        int lz = __builtin_ctzll(m);
                        m &= m - 1;
                        h2 += w2s[lane * N1 + (w * 64 + lz)];
                    }
                }
            }
            v2 += (h2 - v2) * 0.5f;
            bool sp2 = (v2 - 1.0f) >= 0.f;
            unsigned long long bal2 = __ballot(sp2);
            if (sp2) v2 = 0.f;

            float h3 = 0.f;
            if (lane < N3) {
                unsigned long long m = bal2;
                while (m) {
                    int j = __builtin_ctzll(m);
                    m &= m - 1;
                    h3 += w3s[lane * N2 + j];
                }
            }
            v3 += (h3 - v3) * 0.5f;
            bool sp3 = (v3 - 1.0f) >= 0.f;
            if (lane < N3)
                out[(size_t)(t * BATCH + b) * N3 + lane] = sp3 ? 1.f : 0.f;
            if (sp3) v3 = 0.f;
        }
    }
}

extern "C" void kernel_launch(void* const* d_in, const int* in_sizes, int n_in,
                              void* d_out, int out_size, void* d_ws, size_t ws_size,
                              hipStream_t stream) {
    const float* x  = (const float*)d_in[0];   // [16,64,150,400] -> [1024][60000]
    const float* w1 = (const float*)d_in[1];   // [200][60000]
    const float* w2 = (const float*)d_in[2];   // [50][200]
    const float* w3 = (const float*)d_in[3];   // [2][50]
    float* out = (float*)d_out;                // [16][64][2]

    // ws layout: part bf16 [KSPLIT][1024][200], h1 f32, w1b bf16 [256][60000]
    const size_t w1b_bytes = (size_t)NPAD * K_DIM * 2;                 // 30.72 MB
    const size_t h1_bytes  = (size_t)HN * 4;                           // 0.82 MB
    const size_t need75 = (size_t)75 * HN * 2 + h1_bytes + w1b_bytes;  // ~62.3 MB
    const bool big = ws_size >= need75;

    const int ksplit = big ? 75 : 25;
    unsigned short* part = (unsigned short*)d_ws;
    float* h1 = (float*)((char*)d_ws + (size_t)ksplit * HN * 2);
    unsigned short* w1b = (unsigned short*)((char*)h1 + h1_bytes);

    cvt_w1<<<(N1 * K_DIM / 8 + 255) / 256, 256, 0, stream>>>(w1, w1b);
    if (big) {
        dim3 g(16, 75);
        gemm_lds<800, 25, 1200><<<g, 256, 0, stream>>>(x, w1b, part);
        reduce_kernel<75><<<HN / 512, 256, 0, stream>>>(part, h1);
    } else {
        dim3 g(16, 25);
        gemm_lds<2400, 75, 400><<<g, 256, 0, stream>>>(x, w1b, part);
        reduce_kernel<25><<<HN / 512, 256, 0, stream>>>(part, h1);
    }
    tail_kernel<<<BATCH, 256, 0, stream>>>(h1, w2, w3, out);
}